// Round 6
// baseline (269.617 us; speedup 1.0000x reference)
//
#include <hip/hip_runtime.h>
#include <hip/hip_bf16.h>

// Problem constants
#define B_   4
#define C_   32
#define H_   192
#define W_   192
#define HW_  (H_ * W_)          // 36864 = 144 * 256 = 36 * 1024
#define EPS_ 1e-5f

// BETA/ln2 and ln2/BETA (logsumexp in base 2 for the HW exp2/log2 pipe)
#define SCALE_IN  21.640425613334453f
#define SCALE_OUT 0.046209812037329687f

#define NP1 (128 * 4 * 144)     // BN1 partials: chan-major, chan*(4*144) + b*144 + pblk
#define NP2 (32 * 4 * 144)      // BN2 partials: chan-major, c*(4*144) + b*144 + pblk

// ---------------------------------------------------------------------------
// Module-global scratch. No atomics; block-private partial slots.
//   g_stats[0..127] sc1   [128..255] sh1   [256..287] sc2   [288..319] sh2
//   g_D : dilate output, bf16, [(br*B+b)*C+c][p]
//   g_E : erode  output, bf16, [(br*B+b)*C+c][p]
//   g_Y : conv   output, f32,  [(b*C+o)][p]
// ---------------------------------------------------------------------------
__device__ float          g_stats[320];
__device__ float          g_p1[2 * NP1];
__device__ float          g_p2[2 * NP2];
__device__ __hip_bfloat16 g_D[(size_t)4 * B_ * C_ * HW_];   // 37.75 MB
__device__ __hip_bfloat16 g_E[(size_t)4 * B_ * C_ * HW_];   // 37.75 MB
__device__ float          g_Y[(size_t)B_ * C_ * HW_];       // 18.87 MB

// ---------------------------------------------------------------------------
// all-branch soft dilate. grid (144, 32, 16), z = br*B + b
// ---------------------------------------------------------------------------
__global__ __launch_bounds__(256) void dilate_all(const float* __restrict__ x,
                                                  const float* __restrict__ wd) {
    const int z  = blockIdx.z;
    const int br = z >> 2;            // B_ == 4
    const int b  = z & 3;
    const int d  = br + 1;
    const int p  = blockIdx.x * 256 + threadIdx.x;
    const int c  = blockIdx.y;
    const int h  = p / W_;
    const int w  = p - h * W_;

    const float* xp = x + (size_t)(b * C_ + c) * HW_;
    const float* wt = wd + (size_t)(br * C_ + c) * 9;

    float t[9];
    float m = -1e30f;
#pragma unroll
    for (int i = 0; i < 3; i++) {
#pragma unroll
        for (int j = 0; j < 3; j++) {
            const int hh = h + (i - 1) * d;
            const int ww = w + (j - 1) * d;
            float xv = 0.0f;
            if (hh >= 0 && hh < H_ && ww >= 0 && ww < W_) xv = xp[hh * W_ + ww];
            const float v = (xv + wt[i * 3 + j]) * SCALE_IN;
            t[i * 3 + j] = v;
            m = fmaxf(m, v);
        }
    }
    float s = 0.0f;
#pragma unroll
    for (int k = 0; k < 9; k++) s += exp2f(t[k] - m);
    g_D[((size_t)z * C_ + c) * HW_ + p] = __float2bfloat16((m + log2f(s)) * SCALE_OUT);
}

// ---------------------------------------------------------------------------
// all-branch soft erode + BN1 block partials. grid (144, 32, 16), z = br*B + b
// ---------------------------------------------------------------------------
__global__ __launch_bounds__(256) void erode_all(const float* __restrict__ we) {
    const int z  = blockIdx.z;
    const int br = z >> 2;
    const int b  = z & 3;
    const int d  = br + 1;
    const int p  = blockIdx.x * 256 + threadIdx.x;
    const int c  = blockIdx.y;
    const int h  = p / W_;
    const int w  = p - h * W_;

    const __hip_bfloat16* Dp = g_D + ((size_t)z * C_ + c) * HW_;
    const float* wt = we + (size_t)(br * C_ + c) * 9;

    float t[9];
    float m = -1e30f;
#pragma unroll
    for (int i = 0; i < 3; i++) {
#pragma unroll
        for (int j = 0; j < 3; j++) {
            const int hh = h + (i - 1) * d;
            const int ww = w + (j - 1) * d;
            float dv = 0.0f;
            if (hh >= 0 && hh < H_ && ww >= 0 && ww < W_)
                dv = __bfloat162float(Dp[hh * W_ + ww]);
            const float v = (wt[i * 3 + j] - dv) * SCALE_IN;
            t[i * 3 + j] = v;
            m = fmaxf(m, v);
        }
    }
    float s = 0.0f;
#pragma unroll
    for (int k = 0; k < 9; k++) s += exp2f(t[k] - m);
    const float val = -(m + log2f(s)) * SCALE_OUT;

    g_E[((size_t)z * C_ + c) * HW_ + p] = __float2bfloat16(val);

    // block partials (no atomics)
    float s1 = val;
    float s2 = val * val;
#pragma unroll
    for (int off = 32; off >= 1; off >>= 1) {
        s1 += __shfl_down(s1, off, 64);
        s2 += __shfl_down(s2, off, 64);
    }
    __shared__ float l1[4], l2[4];
    const int lane = threadIdx.x & 63;
    const int wv   = threadIdx.x >> 6;
    if (lane == 0) { l1[wv] = s1; l2[wv] = s2; }
    __syncthreads();
    if (threadIdx.x == 0) {
        const int slot = (br * C_ + c) * (B_ * 144) + b * 144 + blockIdx.x;
        g_p1[slot]       = l1[0] + l1[1] + l1[2] + l1[3];
        g_p1[NP1 + slot] = l2[0] + l2[1] + l2[2] + l2[3];
    }
}

// ---------------------------------------------------------------------------
// finalize BN1: reduce 576 partials per channel. grid = 128 blocks
// ---------------------------------------------------------------------------
__global__ __launch_bounds__(256) void fin1_k(const float* __restrict__ gs,
                                              const float* __restrict__ bs) {
    const int chan = blockIdx.x;
    const int base = chan * (B_ * 144);
    float s1 = 0.0f, s2 = 0.0f;
    for (int i = threadIdx.x; i < B_ * 144; i += 256) {
        s1 += g_p1[base + i];
        s2 += g_p1[NP1 + base + i];
    }
#pragma unroll
    for (int off = 32; off >= 1; off >>= 1) {
        s1 += __shfl_down(s1, off, 64);
        s2 += __shfl_down(s2, off, 64);
    }
    __shared__ float l1[4], l2[4];
    const int lane = threadIdx.x & 63;
    const int wv   = threadIdx.x >> 6;
    if (lane == 0) { l1[wv] = s1; l2[wv] = s2; }
    __syncthreads();
    if (threadIdx.x == 0) {
        const float S1 = l1[0] + l1[1] + l1[2] + l1[3];
        const float S2 = l2[0] + l2[1] + l2[2] + l2[3];
        const float N  = (float)(B_ * HW_);
        const float mu = S1 / N;
        const float va = fmaxf(S2 / N - mu * mu, 0.0f);
        const float sc = gs[chan] * rsqrtf(va + EPS_);
        g_stats[chan]       = sc;
        g_stats[128 + chan] = bs[chan] - mu * sc;
    }
}

// ---------------------------------------------------------------------------
// fused BN1+ReLU + 1x1 conv + BN2 block partials.
// grid (144, 4 o-groups, 4 b), 256 threads; thread = 1 pixel x 8 outputs.
// ---------------------------------------------------------------------------
__global__ __launch_bounds__(256) void conv_k(const float* __restrict__ Wc) {
    const int og = blockIdx.y;            // output group: channels og*8 .. og*8+7
    const int b  = blockIdx.z;
    const int p  = blockIdx.x * 256 + threadIdx.x;

    __shared__ float sW[8 * 128];
    __shared__ float ssc[128], ssh[128];
    for (int i = threadIdx.x; i < 8 * 128; i += 256) {
        const int k  = i >> 7;            // 0..7
        const int ci = i & 127;
        sW[i] = Wc[(size_t)(og * 8 + k) * 128 + ci];
    }
    if (threadIdx.x < 128) {
        ssc[threadIdx.x] = g_stats[threadIdx.x];
        ssh[threadIdx.x] = g_stats[128 + threadIdx.x];
    }
    __syncthreads();

    float acc[8];
#pragma unroll
    for (int k = 0; k < 8; k++) acc[k] = 0.0f;

    for (int ci = 0; ci < 128; ci++) {
        // ci = br*32 + c ; E index ((br*B+b)*C+c)*HW = ((ci>>5)*B+b)*C+(ci&31)
        const int br = ci >> 5;
        const int c  = ci & 31;
        float v = __bfloat162float(g_E[(((size_t)br * B_ + b) * C_ + c) * HW_ + p]);
        v = fmaxf(v * ssc[ci] + ssh[ci], 0.0f);
#pragma unroll
        for (int k = 0; k < 8; k++) acc[k] += v * sW[k * 128 + ci];
    }

    float* Yp = g_Y + ((size_t)b * C_ + og * 8) * HW_ + p;
#pragma unroll
    for (int k = 0; k < 8; k++) Yp[(size_t)k * HW_] = acc[k];

    // BN2 block partials for the 8 channels this block produced
    __shared__ float l1[8][4], l2[8][4];
    const int lane = threadIdx.x & 63;
    const int wv   = threadIdx.x >> 6;
#pragma unroll
    for (int k = 0; k < 8; k++) {
        float s1 = acc[k];
        float s2 = acc[k] * acc[k];
#pragma unroll
        for (int off = 32; off >= 1; off >>= 1) {
            s1 += __shfl_down(s1, off, 64);
            s2 += __shfl_down(s2, off, 64);
        }
        if (lane == 0) { l1[k][wv] = s1; l2[k][wv] = s2; }
    }
    __syncthreads();
    if (threadIdx.x < 8) {
        const int k = threadIdx.x;
        const int chan = og * 8 + k;
        const int slot = chan * (B_ * 144) + b * 144 + blockIdx.x;
        g_p2[slot]       = l1[k][0] + l1[k][1] + l1[k][2] + l1[k][3];
        g_p2[NP2 + slot] = l2[k][0] + l2[k][1] + l2[k][2] + l2[k][3];
    }
}

// ---------------------------------------------------------------------------
// finalize BN2: reduce 576 partials per channel. grid = 32 blocks
// ---------------------------------------------------------------------------
__global__ __launch_bounds__(256) void fin2_k(const float* __restrict__ g,
                                              const float* __restrict__ bb) {
    const int chan = blockIdx.x;
    const int base = chan * (B_ * 144);
    float s1 = 0.0f, s2 = 0.0f;
    for (int i = threadIdx.x; i < B_ * 144; i += 256) {
        s1 += g_p2[base + i];
        s2 += g_p2[NP2 + base + i];
    }
#pragma unroll
    for (int off = 32; off >= 1; off >>= 1) {
        s1 += __shfl_down(s1, off, 64);
        s2 += __shfl_down(s2, off, 64);
    }
    __shared__ float l1[4], l2[4];
    const int lane = threadIdx.x & 63;
    const int wv   = threadIdx.x >> 6;
    if (lane == 0) { l1[wv] = s1; l2[wv] = s2; }
    __syncthreads();
    if (threadIdx.x == 0) {
        const float S1 = l1[0] + l1[1] + l1[2] + l1[3];
        const float S2 = l2[0] + l2[1] + l2[2] + l2[3];
        const float N  = (float)(B_ * HW_);
        const float mu = S1 / N;
        const float va = fmaxf(S2 / N - mu * mu, 0.0f);
        const float sc = g[chan] * rsqrtf(va + EPS_);
        g_stats[256 + chan] = sc;
        g_stats[288 + chan] = bb[chan] - mu * sc;
    }
}

// ---------------------------------------------------------------------------
// final: BN2 + ReLU -> f32 out (float4). grid (36, 32, 4)
// ---------------------------------------------------------------------------
__global__ __launch_bounds__(256) void final_k(float* __restrict__ out) {
    const int c = blockIdx.y;
    const int b = blockIdx.z;
    const size_t base = (size_t)(b * C_ + c) * HW_ + (blockIdx.x * 256 + threadIdx.x) * 4;
    const float sc = g_stats[256 + c];
    const float sh = g_stats[288 + c];
    const float4 v = *(const float4*)&g_Y[base];
    float4 r;
    r.x = fmaxf(v.x * sc + sh, 0.0f);
    r.y = fmaxf(v.y * sc + sh, 0.0f);
    r.z = fmaxf(v.z * sc + sh, 0.0f);
    r.w = fmaxf(v.w * sc + sh, 0.0f);
    *(float4*)&out[base] = r;
}

// ---------------------------------------------------------------------------
extern "C" void kernel_launch(void* const* d_in, const int* in_sizes, int n_in,
                              void* d_out, int out_size, void* d_ws, size_t ws_size,
                              hipStream_t stream) {
    const float* x  = (const float*)d_in[0];
    const float* wd = (const float*)d_in[1];
    const float* we = (const float*)d_in[2];
    const float* gs = (const float*)d_in[3];
    const float* bs = (const float*)d_in[4];
    const float* Wc = (const float*)d_in[5];
    const float* g  = (const float*)d_in[6];
    const float* bb = (const float*)d_in[7];

    const dim3 gridM(HW_ / 256, C_, 4 * B_);
    dilate_all<<<gridM, 256, 0, stream>>>(x, wd);
    erode_all<<<gridM, 256, 0, stream>>>(we);
    fin1_k<<<128, 256, 0, stream>>>(gs, bs);
    conv_k<<<dim3(HW_ / 256, 4, B_), 256, 0, stream>>>(Wc);
    fin2_k<<<32, 256, 0, stream>>>(g, bb);
    final_k<<<dim3(HW_ / 1024, C_, B_), 256, 0, stream>>>((float*)d_out);
}

// Round 7
// 201.243 us; speedup vs baseline: 1.3398x; 1.3398x over previous
//
#include <hip/hip_runtime.h>
#include <hip/hip_bf16.h>

// Problem constants
#define B_   4
#define C_   32
#define H_   192
#define W_   192
#define HW_  (H_ * W_)          // 36864 = 144 * 256
#define EPS_ 1e-5f

#define WP_   200               // padded width/height (4-halo both sides)
#define MAP_  (WP_ * WP_)       // 40000 cells per padded map
#define SCALE_IN  21.640425613334453f   // beta/ln2
#define SCALE_OUT 0.046209812037329687f // ln2/beta

#define NP1 (128 * 4 * 144)
#define NP2 (32 * 4 * 144)

// ---------------------------------------------------------------------------
// Scratch (module globals; no atomics anywhere).
//  g_cw[0..1151] = 2^(s*wd), [1152..2303] = 2^(s*we)   (layout (br*C+c)*9+tap)
//  g_P : padded 2^(s*x),  128 maps (b*C+c), border = 0
//  g_Q : padded 1/S_dil,  512 maps ((br*B+b)*C+c), border = 1
//  g_E : erode out, bf16, [(br*B+b)*C+c][p]
//  g_Y : conv out,  f32,  [(b*C+o)][p]
//  g_stats[0..127] sc1 [128..255] sh1 [256..287] sc2 [288..319] sh2
// ---------------------------------------------------------------------------
__device__ float          g_cw[2304];
__device__ float          g_stats[320];
__device__ float          g_p1[2 * NP1];
__device__ float          g_p2[2 * NP2];
__device__ float          g_P[(size_t)B_ * C_ * MAP_];        // 20.5 MB
__device__ float          g_Q[(size_t)4 * B_ * C_ * MAP_];    // 81.9 MB
__device__ __hip_bfloat16 g_E[(size_t)4 * B_ * C_ * HW_];     // 37.75 MB
__device__ float          g_Y[(size_t)B_ * C_ * HW_];         // 18.87 MB

// ---------------------------------------------------------------------------
// prep: exponentiate the morphology weights (2304 values)
// ---------------------------------------------------------------------------
__global__ void prep_k(const float* __restrict__ wd, const float* __restrict__ we) {
    for (int i = threadIdx.x; i < 2304; i += 256) {
        const float v = (i < 1152) ? wd[i] : we[i - 1152];
        g_cw[i] = exp2f(SCALE_IN * v);
    }
}

// ---------------------------------------------------------------------------
// pass A: P = 2^(s*x) into padded maps (border 0). grid (40, 128)
// ---------------------------------------------------------------------------
__global__ __launch_bounds__(256) void pA_k(const float* __restrict__ x) {
    const int v = blockIdx.x * 256 + threadIdx.x;
    if (v >= MAP_ / 4) return;
    const int m   = blockIdx.y;               // b*C + c
    const int p4  = v * 4;
    const int ph  = p4 / WP_;                 // WP_ % 4 == 0 -> same row
    const int pw0 = p4 - ph * WP_;

    float4 r = make_float4(0.f, 0.f, 0.f, 0.f);
    if (ph >= 4 && ph < 196) {
        const float* xm = x + (size_t)m * HW_;
#pragma unroll
        for (int k = 0; k < 4; k++) {
            const int pw = pw0 + k;
            if (pw >= 4 && pw < 196)
                (&r.x)[k] = exp2f(SCALE_IN * xm[(ph - 4) * W_ + (pw - 4)]);
        }
    }
    *(float4*)&g_P[(size_t)m * MAP_ + p4] = r;
}

// ---------------------------------------------------------------------------
// pass B: Q = 1 / (sum_ij cd_ij * P_tap)  (padded; border cells = 1)
// grid (157, 32, 16), z = br*B + b. Tap offsets compile-time via template.
// ---------------------------------------------------------------------------
template<int D>
__device__ __forceinline__ float q_compute(const float* __restrict__ Pm,
                                           const float* __restrict__ cw,
                                           int ph, int pw) {
    float s = 0.f;
#pragma unroll
    for (int i = 0; i < 3; i++)
#pragma unroll
        for (int j = 0; j < 3; j++)
            s = fmaf(cw[i * 3 + j], Pm[(ph + (i - 1) * D) * WP_ + pw + (j - 1) * D], s);
    return 1.0f / s;
}

__global__ __launch_bounds__(256) void qk(void) {
    const int p = blockIdx.x * 256 + threadIdx.x;
    if (p >= MAP_) return;
    const int z  = blockIdx.z;
    const int br = z >> 2;
    const int b  = z & 3;
    const int c  = blockIdx.y;
    const int ph = p / WP_;
    const int pw = p - ph * WP_;

    float q = 1.0f;
    if (ph >= 4 && ph < 196 && pw >= 4 && pw < 196) {
        const float* Pm = g_P + (size_t)(b * C_ + c) * MAP_;
        const float* cw = g_cw + (size_t)(br * C_ + c) * 9;
        switch (br) {
            case 0: q = q_compute<1>(Pm, cw, ph, pw); break;
            case 1: q = q_compute<2>(Pm, cw, ph, pw); break;
            case 2: q = q_compute<3>(Pm, cw, ph, pw); break;
            default: q = q_compute<4>(Pm, cw, ph, pw); break;
        }
    }
    g_Q[((size_t)z * C_ + c) * MAP_ + p] = q;
}

// ---------------------------------------------------------------------------
// pass C: E = -(ln2/beta) * log2( sum_ij ce_ij * Q_tap ), + BN1 partials
// grid (144, 32, 16), z = br*B + b
// ---------------------------------------------------------------------------
template<int D>
__device__ __forceinline__ float e_compute(const float* __restrict__ Qm,
                                           const float* __restrict__ cw,
                                           int ph, int pw) {
    float t = 0.f;
#pragma unroll
    for (int i = 0; i < 3; i++)
#pragma unroll
        for (int j = 0; j < 3; j++)
            t = fmaf(cw[i * 3 + j], Qm[(ph + (i - 1) * D) * WP_ + pw + (j - 1) * D], t);
    return -SCALE_OUT * log2f(t);
}

__global__ __launch_bounds__(256) void ek(void) {
    const int p  = blockIdx.x * 256 + threadIdx.x;     // exact
    const int z  = blockIdx.z;
    const int br = z >> 2;
    const int b  = z & 3;
    const int c  = blockIdx.y;
    const int h  = p / W_;
    const int w  = p - h * W_;
    const int ph = h + 4, pw = w + 4;

    const float* Qm = g_Q + ((size_t)z * C_ + c) * MAP_;
    const float* cw = g_cw + 1152 + (size_t)(br * C_ + c) * 9;

    float val;
    switch (br) {
        case 0: val = e_compute<1>(Qm, cw, ph, pw); break;
        case 1: val = e_compute<2>(Qm, cw, ph, pw); break;
        case 2: val = e_compute<3>(Qm, cw, ph, pw); break;
        default: val = e_compute<4>(Qm, cw, ph, pw); break;
    }

    g_E[((size_t)z * C_ + c) * HW_ + p] = __float2bfloat16(val);

    float s1 = val;
    float s2 = val * val;
#pragma unroll
    for (int off = 32; off >= 1; off >>= 1) {
        s1 += __shfl_down(s1, off, 64);
        s2 += __shfl_down(s2, off, 64);
    }
    __shared__ float l1[4], l2[4];
    const int lane = threadIdx.x & 63;
    const int wv   = threadIdx.x >> 6;
    if (lane == 0) { l1[wv] = s1; l2[wv] = s2; }
    __syncthreads();
    if (threadIdx.x == 0) {
        const int slot = (br * C_ + c) * (B_ * 144) + b * 144 + blockIdx.x;
        g_p1[slot]       = l1[0] + l1[1] + l1[2] + l1[3];
        g_p1[NP1 + slot] = l2[0] + l2[1] + l2[2] + l2[3];
    }
}

// ---------------------------------------------------------------------------
// finalize BN1: reduce 576 partials per channel. grid = 128
// ---------------------------------------------------------------------------
__global__ __launch_bounds__(256) void fin1_k(const float* __restrict__ gs,
                                              const float* __restrict__ bs) {
    const int chan = blockIdx.x;
    const int base = chan * (B_ * 144);
    float s1 = 0.0f, s2 = 0.0f;
    for (int i = threadIdx.x; i < B_ * 144; i += 256) {
        s1 += g_p1[base + i];
        s2 += g_p1[NP1 + base + i];
    }
#pragma unroll
    for (int off = 32; off >= 1; off >>= 1) {
        s1 += __shfl_down(s1, off, 64);
        s2 += __shfl_down(s2, off, 64);
    }
    __shared__ float l1[4], l2[4];
    const int lane = threadIdx.x & 63;
    const int wv   = threadIdx.x >> 6;
    if (lane == 0) { l1[wv] = s1; l2[wv] = s2; }
    __syncthreads();
    if (threadIdx.x == 0) {
        const float S1 = l1[0] + l1[1] + l1[2] + l1[3];
        const float S2 = l2[0] + l2[1] + l2[2] + l2[3];
        const float N  = (float)(B_ * HW_);
        const float mu = S1 / N;
        const float va = fmaxf(S2 / N - mu * mu, 0.0f);
        const float sc = gs[chan] * rsqrtf(va + EPS_);
        g_stats[chan]       = sc;
        g_stats[128 + chan] = bs[chan] - mu * sc;
    }
}

// ---------------------------------------------------------------------------
// fused BN1+ReLU + 1x1 conv + BN2 partials. grid (144, 4, 4): og, b
// ---------------------------------------------------------------------------
__global__ __launch_bounds__(256) void conv_k(const float* __restrict__ Wc) {
    const int og = blockIdx.y;
    const int b  = blockIdx.z;
    const int p  = blockIdx.x * 256 + threadIdx.x;

    __shared__ float sW[8 * 128];
    __shared__ float ssc[128], ssh[128];
    for (int i = threadIdx.x; i < 8 * 128; i += 256) {
        const int k  = i >> 7;
        const int ci = i & 127;
        sW[i] = Wc[(size_t)(og * 8 + k) * 128 + ci];
    }
    if (threadIdx.x < 128) {
        ssc[threadIdx.x] = g_stats[threadIdx.x];
        ssh[threadIdx.x] = g_stats[128 + threadIdx.x];
    }
    __syncthreads();

    float acc[8];
#pragma unroll
    for (int k = 0; k < 8; k++) acc[k] = 0.0f;

    for (int ci = 0; ci < 128; ci++) {
        const int br = ci >> 5;
        const int c  = ci & 31;
        float v = __bfloat162float(g_E[(((size_t)br * B_ + b) * C_ + c) * HW_ + p]);
        v = fmaxf(v * ssc[ci] + ssh[ci], 0.0f);
#pragma unroll
        for (int k = 0; k < 8; k++) acc[k] += v * sW[k * 128 + ci];
    }

    float* Yp = g_Y + ((size_t)b * C_ + og * 8) * HW_ + p;
#pragma unroll
    for (int k = 0; k < 8; k++) Yp[(size_t)k * HW_] = acc[k];

    __shared__ float l1[8][4], l2[8][4];
    const int lane = threadIdx.x & 63;
    const int wv   = threadIdx.x >> 6;
#pragma unroll
    for (int k = 0; k < 8; k++) {
        float s1 = acc[k];
        float s2 = acc[k] * acc[k];
#pragma unroll
        for (int off = 32; off >= 1; off >>= 1) {
            s1 += __shfl_down(s1, off, 64);
            s2 += __shfl_down(s2, off, 64);
        }
        if (lane == 0) { l1[k][wv] = s1; l2[k][wv] = s2; }
    }
    __syncthreads();
    if (threadIdx.x < 8) {
        const int k = threadIdx.x;
        const int chan = og * 8 + k;
        const int slot = chan * (B_ * 144) + b * 144 + blockIdx.x;
        g_p2[slot]       = l1[k][0] + l1[k][1] + l1[k][2] + l1[k][3];
        g_p2[NP2 + slot] = l2[k][0] + l2[k][1] + l2[k][2] + l2[k][3];
    }
}

// ---------------------------------------------------------------------------
// finalize BN2: reduce 576 partials per channel. grid = 32
// ---------------------------------------------------------------------------
__global__ __launch_bounds__(256) void fin2_k(const float* __restrict__ g,
                                              const float* __restrict__ bb) {
    const int chan = blockIdx.x;
    const int base = chan * (B_ * 144);
    float s1 = 0.0f, s2 = 0.0f;
    for (int i = threadIdx.x; i < B_ * 144; i += 256) {
        s1 += g_p2[base + i];
        s2 += g_p2[NP2 + base + i];
    }
#pragma unroll
    for (int off = 32; off >= 1; off >>= 1) {
        s1 += __shfl_down(s1, off, 64);
        s2 += __shfl_down(s2, off, 64);
    }
    __shared__ float l1[4], l2[4];
    const int lane = threadIdx.x & 63;
    const int wv   = threadIdx.x >> 6;
    if (lane == 0) { l1[wv] = s1; l2[wv] = s2; }
    __syncthreads();
    if (threadIdx.x == 0) {
        const float S1 = l1[0] + l1[1] + l1[2] + l1[3];
        const float S2 = l2[0] + l2[1] + l2[2] + l2[3];
        const float N  = (float)(B_ * HW_);
        const float mu = S1 / N;
        const float va = fmaxf(S2 / N - mu * mu, 0.0f);
        const float sc = g[chan] * rsqrtf(va + EPS_);
        g_stats[256 + chan] = sc;
        g_stats[288 + chan] = bb[chan] - mu * sc;
    }
}

// ---------------------------------------------------------------------------
// final: BN2 + ReLU -> f32 (float4). grid (36, 32, 4)
// ---------------------------------------------------------------------------
__global__ __launch_bounds__(256) void final_k(float* __restrict__ out) {
    const int c = blockIdx.y;
    const int b = blockIdx.z;
    const size_t base = (size_t)(b * C_ + c) * HW_ + (blockIdx.x * 256 + threadIdx.x) * 4;
    const float sc = g_stats[256 + c];
    const float sh = g_stats[288 + c];
    const float4 v = *(const float4*)&g_Y[base];
    float4 r;
    r.x = fmaxf(v.x * sc + sh, 0.0f);
    r.y = fmaxf(v.y * sc + sh, 0.0f);
    r.z = fmaxf(v.z * sc + sh, 0.0f);
    r.w = fmaxf(v.w * sc + sh, 0.0f);
    *(float4*)&out[base] = r;
}

// ---------------------------------------------------------------------------
extern "C" void kernel_launch(void* const* d_in, const int* in_sizes, int n_in,
                              void* d_out, int out_size, void* d_ws, size_t ws_size,
                              hipStream_t stream) {
    const float* x  = (const float*)d_in[0];
    const float* wd = (const float*)d_in[1];
    const float* we = (const float*)d_in[2];
    const float* gs = (const float*)d_in[3];
    const float* bs = (const float*)d_in[4];
    const float* Wc = (const float*)d_in[5];
    const float* g  = (const float*)d_in[6];
    const float* bb = (const float*)d_in[7];

    prep_k<<<1, 256, 0, stream>>>(wd, we);
    pA_k<<<dim3((MAP_ / 4 + 255) / 256, B_ * C_), 256, 0, stream>>>(x);
    qk<<<dim3((MAP_ + 255) / 256, C_, 4 * B_), 256, 0, stream>>>();
    ek<<<dim3(HW_ / 256, C_, 4 * B_), 256, 0, stream>>>();
    fin1_k<<<128, 256, 0, stream>>>(gs, bs);
    conv_k<<<dim3(HW_ / 256, 4, B_), 256, 0, stream>>>(Wc);
    fin2_k<<<32, 256, 0, stream>>>(g, bb);
    final_k<<<dim3(HW_ / 1024, C_, B_), 256, 0, stream>>>((float*)d_out);
}

// Round 8
// 172.771 us; speedup vs baseline: 1.5605x; 1.1648x over previous
//
#include <hip/hip_runtime.h>
#include <hip/hip_bf16.h>

// Problem constants
#define B_   4
#define C_   32
#define H_   192
#define W_   192
#define HW_  (H_ * W_)          // 36864 = 144 * 256
#define EPS_ 1e-5f

#define WP_   200               // padded width/height (4-halo both sides)
#define MAP_  (WP_ * WP_)       // 40000 cells per padded map
#define SCALE_IN  21.640425613334453f   // beta/ln2
#define SCALE_OUT 0.046209812037329687f // ln2/beta

#define NP1 (128 * 4 * 144)
#define NP2 (32 * 4 * 144)

// bf16 <-> f32 helpers (bit-exact shift load, RNE store)
__device__ __forceinline__ float bf2f(unsigned short u) {
    return __uint_as_float((unsigned int)u << 16);
}
__device__ __forceinline__ unsigned short f2bf(float f) {
    const unsigned int u = __float_as_uint(f);
    return (unsigned short)((u + 0x7fffu + ((u >> 16) & 1u)) >> 16);
}

// ---------------------------------------------------------------------------
// Scratch (module globals; no atomics anywhere).
//  g_cw[0..1151] = 2^(s*wd), [1152..2303] = 2^(s*we)   ((br*C+c)*9+tap)
//  g_Wt[ci*32+k] = Wc[k*128+ci]  (transposed 1x1-conv weights, f32)
//  g_stats[0..127] sc1 [128..255] sh1 [256..287] sc2 [288..319] sh2
//  g_P : padded 2^(s*x), bf16, 128 maps (b*C+c), border = 0
//  g_Q : padded 1/S_dil, bf16, 512 maps ((br*B+b)*C+c), border = 1
//  g_E : erode out, bf16 bits, [(br*B+b)*C+c][p]
//  g_Y : conv out,  f32,  [(b*C+o)][p]
// ---------------------------------------------------------------------------
__device__ float          g_cw[2304];
__device__ float          g_Wt[4096];
__device__ float          g_stats[320];
__device__ float          g_p1[2 * NP1];
__device__ float          g_p2[2 * NP2];
__device__ unsigned short g_P[(size_t)B_ * C_ * MAP_];        // 10.2 MB
__device__ unsigned short g_Q[(size_t)4 * B_ * C_ * MAP_];    // 41.0 MB
__device__ unsigned short g_E[(size_t)4 * B_ * C_ * HW_];     // 37.75 MB
__device__ float          g_Y[(size_t)B_ * C_ * HW_];         // 18.87 MB

// ---------------------------------------------------------------------------
// prep: exponentiate morphology weights + transpose conv weights
// ---------------------------------------------------------------------------
__global__ void prep_k(const float* __restrict__ wd, const float* __restrict__ we,
                       const float* __restrict__ Wc) {
    for (int i = threadIdx.x; i < 2304; i += 256) {
        const float v = (i < 1152) ? wd[i] : we[i - 1152];
        g_cw[i] = exp2f(SCALE_IN * v);
    }
    for (int i = threadIdx.x; i < 4096; i += 256) {
        const int ci = i >> 5;
        const int k  = i & 31;
        g_Wt[i] = Wc[(size_t)k * 128 + ci];
    }
}

// ---------------------------------------------------------------------------
// pass A: P = 2^(s*x) into padded bf16 maps (border 0). grid (40, 128)
// ---------------------------------------------------------------------------
__global__ __launch_bounds__(256) void pA_k(const float* __restrict__ x) {
    const int v = blockIdx.x * 256 + threadIdx.x;
    if (v >= MAP_ / 4) return;
    const int m   = blockIdx.y;               // b*C + c
    const int p4  = v * 4;
    const int ph  = p4 / WP_;                 // WP_ % 4 == 0 -> same row
    const int pw0 = p4 - ph * WP_;

    ushort4 r = make_ushort4(0, 0, 0, 0);
    if (ph >= 4 && ph < 196) {
        const float* xm = x + (size_t)m * HW_;
#pragma unroll
        for (int k = 0; k < 4; k++) {
            const int pw = pw0 + k;
            if (pw >= 4 && pw < 196)
                (&r.x)[k] = f2bf(exp2f(SCALE_IN * xm[(ph - 4) * W_ + (pw - 4)]));
        }
    }
    *(ushort4*)&g_P[(size_t)m * MAP_ + p4] = r;
}

// ---------------------------------------------------------------------------
// pass B: Q = 1 / (sum_ij cd_ij * P_tap)  (padded; border cells = 1)
// grid (157, 32, 16), z = br*B + b. Tap offsets compile-time via template.
// ---------------------------------------------------------------------------
template<int D>
__device__ __forceinline__ float q_compute(const unsigned short* __restrict__ Pm,
                                           const float* __restrict__ cw,
                                           int ph, int pw) {
    float s = 0.f;
#pragma unroll
    for (int i = 0; i < 3; i++)
#pragma unroll
        for (int j = 0; j < 3; j++)
            s = fmaf(cw[i * 3 + j], bf2f(Pm[(ph + (i - 1) * D) * WP_ + pw + (j - 1) * D]), s);
    return 1.0f / s;
}

__global__ __launch_bounds__(256) void qk(void) {
    const int p = blockIdx.x * 256 + threadIdx.x;
    if (p >= MAP_) return;
    const int z  = blockIdx.z;
    const int br = z >> 2;
    const int b  = z & 3;
    const int c  = blockIdx.y;
    const int ph = p / WP_;
    const int pw = p - ph * WP_;

    float q = 1.0f;
    if (ph >= 4 && ph < 196 && pw >= 4 && pw < 196) {
        const unsigned short* Pm = g_P + (size_t)(b * C_ + c) * MAP_;
        const float* cw = g_cw + (size_t)(br * C_ + c) * 9;
        switch (br) {
            case 0: q = q_compute<1>(Pm, cw, ph, pw); break;
            case 1: q = q_compute<2>(Pm, cw, ph, pw); break;
            case 2: q = q_compute<3>(Pm, cw, ph, pw); break;
            default: q = q_compute<4>(Pm, cw, ph, pw); break;
        }
    }
    g_Q[((size_t)z * C_ + c) * MAP_ + p] = f2bf(q);
}

// ---------------------------------------------------------------------------
// pass C: E = -(ln2/beta) * log2( sum_ij ce_ij * Q_tap ), + BN1 partials
// grid (144, 32, 16), z = br*B + b
// ---------------------------------------------------------------------------
template<int D>
__device__ __forceinline__ float e_compute(const unsigned short* __restrict__ Qm,
                                           const float* __restrict__ cw,
                                           int ph, int pw) {
    float t = 0.f;
#pragma unroll
    for (int i = 0; i < 3; i++)
#pragma unroll
        for (int j = 0; j < 3; j++)
            t = fmaf(cw[i * 3 + j], bf2f(Qm[(ph + (i - 1) * D) * WP_ + pw + (j - 1) * D]), t);
    return -SCALE_OUT * log2f(t);
}

__global__ __launch_bounds__(256) void ek(void) {
    const int p  = blockIdx.x * 256 + threadIdx.x;     // exact
    const int z  = blockIdx.z;
    const int br = z >> 2;
    const int b  = z & 3;
    const int c  = blockIdx.y;
    const int h  = p / W_;
    const int w  = p - h * W_;
    const int ph = h + 4, pw = w + 4;

    const unsigned short* Qm = g_Q + ((size_t)z * C_ + c) * MAP_;
    const float* cw = g_cw + 1152 + (size_t)(br * C_ + c) * 9;

    float val;
    switch (br) {
        case 0: val = e_compute<1>(Qm, cw, ph, pw); break;
        case 1: val = e_compute<2>(Qm, cw, ph, pw); break;
        case 2: val = e_compute<3>(Qm, cw, ph, pw); break;
        default: val = e_compute<4>(Qm, cw, ph, pw); break;
    }

    g_E[((size_t)z * C_ + c) * HW_ + p] = f2bf(val);

    float s1 = val;
    float s2 = val * val;
#pragma unroll
    for (int off = 32; off >= 1; off >>= 1) {
        s1 += __shfl_down(s1, off, 64);
        s2 += __shfl_down(s2, off, 64);
    }
    __shared__ float l1[4], l2[4];
    const int lane = threadIdx.x & 63;
    const int wv   = threadIdx.x >> 6;
    if (lane == 0) { l1[wv] = s1; l2[wv] = s2; }
    __syncthreads();
    if (threadIdx.x == 0) {
        const int slot = (br * C_ + c) * (B_ * 144) + b * 144 + blockIdx.x;
        g_p1[slot]       = l1[0] + l1[1] + l1[2] + l1[3];
        g_p1[NP1 + slot] = l2[0] + l2[1] + l2[2] + l2[3];
    }
}

// ---------------------------------------------------------------------------
// finalize BN1: reduce 576 partials per channel. grid = 128
// ---------------------------------------------------------------------------
__global__ __launch_bounds__(256) void fin1_k(const float* __restrict__ gs,
                                              const float* __restrict__ bs) {
    const int chan = blockIdx.x;
    const int base = chan * (B_ * 144);
    float s1 = 0.0f, s2 = 0.0f;
    for (int i = threadIdx.x; i < B_ * 144; i += 256) {
        s1 += g_p1[base + i];
        s2 += g_p1[NP1 + base + i];
    }
#pragma unroll
    for (int off = 32; off >= 1; off >>= 1) {
        s1 += __shfl_down(s1, off, 64);
        s2 += __shfl_down(s2, off, 64);
    }
    __shared__ float l1[4], l2[4];
    const int lane = threadIdx.x & 63;
    const int wv   = threadIdx.x >> 6;
    if (lane == 0) { l1[wv] = s1; l2[wv] = s2; }
    __syncthreads();
    if (threadIdx.x == 0) {
        const float S1 = l1[0] + l1[1] + l1[2] + l1[3];
        const float S2 = l2[0] + l2[1] + l2[2] + l2[3];
        const float N  = (float)(B_ * HW_);
        const float mu = S1 / N;
        const float va = fmaxf(S2 / N - mu * mu, 0.0f);
        const float sc = gs[chan] * rsqrtf(va + EPS_);
        g_stats[chan]       = sc;
        g_stats[128 + chan] = bs[chan] - mu * sc;
    }
}

// ---------------------------------------------------------------------------
// fused BN1+ReLU + 1x1 conv + BN2 partials. grid (144, 4 og, 4 b).
// Weights/scales are wave-uniform -> scalar loads (SGPR operands);
// E loaded once per (pixel, ci) as bf16 bits, converted by shift.
// ---------------------------------------------------------------------------
__global__ __launch_bounds__(256) void conv_k(void) {
    const int og = blockIdx.y;            // output channels og*8 .. og*8+7
    const int b  = blockIdx.z;
    const int p  = blockIdx.x * 256 + threadIdx.x;

    float acc[8];
#pragma unroll
    for (int k = 0; k < 8; k++) acc[k] = 0.0f;

#pragma unroll 4
    for (int ci = 0; ci < 128; ci++) {
        const int br = ci >> 5;
        const int c  = ci & 31;
        const unsigned short eu = g_E[(((size_t)br * B_ + b) * C_ + c) * HW_ + p];
        float v = bf2f(eu);
        v = fmaxf(fmaf(v, g_stats[ci], g_stats[128 + ci]), 0.0f);
        const float* wr = &g_Wt[ci * 32 + og * 8];
#pragma unroll
        for (int k = 0; k < 8; k++) acc[k] = fmaf(v, wr[k], acc[k]);
    }

    float* Yp = g_Y + ((size_t)b * C_ + og * 8) * HW_ + p;
#pragma unroll
    for (int k = 0; k < 8; k++) Yp[(size_t)k * HW_] = acc[k];

    // BN2 block partials for the 8 channels this block produced
    __shared__ float l1[8][4], l2[8][4];
    const int lane = threadIdx.x & 63;
    const int wv   = threadIdx.x >> 6;
#pragma unroll
    for (int k = 0; k < 8; k++) {
        float s1 = acc[k];
        float s2 = acc[k] * acc[k];
#pragma unroll
        for (int off = 32; off >= 1; off >>= 1) {
            s1 += __shfl_down(s1, off, 64);
            s2 += __shfl_down(s2, off, 64);
        }
        if (lane == 0) { l1[k][wv] = s1; l2[k][wv] = s2; }
    }
    __syncthreads();
    if (threadIdx.x < 8) {
        const int k = threadIdx.x;
        const int chan = og * 8 + k;
        const int slot = chan * (B_ * 144) + b * 144 + blockIdx.x;
        g_p2[slot]       = l1[k][0] + l1[k][1] + l1[k][2] + l1[k][3];
        g_p2[NP2 + slot] = l2[k][0] + l2[k][1] + l2[k][2] + l2[k][3];
    }
}

// ---------------------------------------------------------------------------
// finalize BN2: reduce 576 partials per channel. grid = 32
// ---------------------------------------------------------------------------
__global__ __launch_bounds__(256) void fin2_k(const float* __restrict__ g,
                                              const float* __restrict__ bb) {
    const int chan = blockIdx.x;
    const int base = chan * (B_ * 144);
    float s1 = 0.0f, s2 = 0.0f;
    for (int i = threadIdx.x; i < B_ * 144; i += 256) {
        s1 += g_p2[base + i];
        s2 += g_p2[NP2 + base + i];
    }
#pragma unroll
    for (int off = 32; off >= 1; off >>= 1) {
        s1 += __shfl_down(s1, off, 64);
        s2 += __shfl_down(s2, off, 64);
    }
    __shared__ float l1[4], l2[4];
    const int lane = threadIdx.x & 63;
    const int wv   = threadIdx.x >> 6;
    if (lane == 0) { l1[wv] = s1; l2[wv] = s2; }
    __syncthreads();
    if (threadIdx.x == 0) {
        const float S1 = l1[0] + l1[1] + l1[2] + l1[3];
        const float S2 = l2[0] + l2[1] + l2[2] + l2[3];
        const float N  = (float)(B_ * HW_);
        const float mu = S1 / N;
        const float va = fmaxf(S2 / N - mu * mu, 0.0f);
        const float sc = g[chan] * rsqrtf(va + EPS_);
        g_stats[256 + chan] = sc;
        g_stats[288 + chan] = bb[chan] - mu * sc;
    }
}

// ---------------------------------------------------------------------------
// final: BN2 + ReLU -> f32 (float4). grid (36, 32, 4)
// ---------------------------------------------------------------------------
__global__ __launch_bounds__(256) void final_k(float* __restrict__ out) {
    const int c = blockIdx.y;
    const int b = blockIdx.z;
    const size_t base = (size_t)(b * C_ + c) * HW_ + (blockIdx.x * 256 + threadIdx.x) * 4;
    const float sc = g_stats[256 + c];
    const float sh = g_stats[288 + c];
    const float4 v = *(const float4*)&g_Y[base];
    float4 r;
    r.x = fmaxf(v.x * sc + sh, 0.0f);
    r.y = fmaxf(v.y * sc + sh, 0.0f);
    r.z = fmaxf(v.z * sc + sh, 0.0f);
    r.w = fmaxf(v.w * sc + sh, 0.0f);
    *(float4*)&out[base] = r;
}

// ---------------------------------------------------------------------------
extern "C" void kernel_launch(void* const* d_in, const int* in_sizes, int n_in,
                              void* d_out, int out_size, void* d_ws, size_t ws_size,
                              hipStream_t stream) {
    const float* x  = (const float*)d_in[0];
    const float* wd = (const float*)d_in[1];
    const float* we = (const float*)d_in[2];
    const float* gs = (const float*)d_in[3];
    const float* bs = (const float*)d_in[4];
    const float* Wc = (const float*)d_in[5];
    const float* g  = (const float*)d_in[6];
    const float* bb = (const float*)d_in[7];

    prep_k<<<1, 256, 0, stream>>>(wd, we, Wc);
    pA_k<<<dim3((MAP_ / 4 + 255) / 256, B_ * C_), 256, 0, stream>>>(x);
    qk<<<dim3((MAP_ + 255) / 256, C_, 4 * B_), 256, 0, stream>>>();
    ek<<<dim3(HW_ / 256, C_, 4 * B_), 256, 0, stream>>>();
    fin1_k<<<128, 256, 0, stream>>>(gs, bs);
    conv_k<<<dim3(HW_ / 256, 4, B_), 256, 0, stream>>>();
    fin2_k<<<32, 256, 0, stream>>>(g, bb);
    final_k<<<dim3(HW_ / 1024, C_, B_), 256, 0, stream>>>((float*)d_out);
}

// Round 9
// 133.644 us; speedup vs baseline: 2.0174x; 1.2928x over previous
//
#include <hip/hip_runtime.h>
#include <hip/hip_bf16.h>

// Problem constants
#define B_   4
#define C_   32
#define H_   192
#define W_   192
#define HW_  (H_ * W_)          // 36864
#define EPS_ 1e-5f

#define PAD_  8                 // P halo: up to 2*D = 8
#define WP_   (W_ + 2 * PAD_)   // 208
#define MAP_  (WP_ * WP_)       // 43264
#define SCALE_IN  21.640425613334453f   // beta/ln2
#define SCALE_OUT 0.046209812037329687f // ln2/beta

#define NP1 (128 * 144)         // chan * (4 b * 36 tiles)
#define NP2 (32 * 4 * 144)

// bf16 <-> f32 helpers (bit-exact shift load, RNE store)
__device__ __forceinline__ float bf2f(unsigned short u) {
    return __uint_as_float((unsigned int)u << 16);
}
__device__ __forceinline__ unsigned short f2bf(float f) {
    const unsigned int u = __float_as_uint(f);
    return (unsigned short)((u + 0x7fffu + ((u >> 16) & 1u)) >> 16);
}

// ---------------------------------------------------------------------------
// Scratch (module globals; no atomics anywhere).
//  g_cw[0..1151] = 2^(s*wd), [1152..2303] = 2^(s*we)   ((br*C+c)*9+tap)
//  g_Wt[ci*32+k] = Wc[k*128+ci]
//  g_stats[0..127] sc1 [128..255] sh1 [256..287] sc2 [288..319] sh2
//  g_P : padded 2^(s*x), bf16, 128 maps (b*C+c); pad ring = 1.0 (= 2^(s*0))
//  g_E : erode out, bf16 bits, [(br*B+b)*C+c][p]
//  g_Y : conv out,  f32,  [(b*C+o)][p]
// ---------------------------------------------------------------------------
__device__ float          g_cw[2304];
__device__ float          g_Wt[4096];
__device__ float          g_stats[320];
__device__ float          g_p1[2 * NP1];
__device__ float          g_p2[2 * NP2];
__device__ __attribute__((aligned(16))) unsigned short g_P[(size_t)B_ * C_ * MAP_];  // 11.1 MB
__device__ __attribute__((aligned(16))) unsigned short g_E[(size_t)4 * B_ * C_ * HW_]; // 37.75 MB
__device__ __attribute__((aligned(16))) float          g_Y[(size_t)B_ * C_ * HW_];     // 18.87 MB

// ---------------------------------------------------------------------------
// prep: exponentiate morphology weights + transpose conv weights
// ---------------------------------------------------------------------------
__global__ void prep_k(const float* __restrict__ wd, const float* __restrict__ we,
                       const float* __restrict__ Wc) {
    for (int i = threadIdx.x; i < 2304; i += 256) {
        const float v = (i < 1152) ? wd[i] : we[i - 1152];
        g_cw[i] = exp2f(SCALE_IN * v);
    }
    for (int i = threadIdx.x; i < 4096; i += 256) {
        const int ci = i >> 5;
        const int k  = i & 31;
        g_Wt[i] = Wc[(size_t)k * 128 + ci];
    }
}

// ---------------------------------------------------------------------------
// pass A: P = 2^(s*x) into padded bf16 maps; pad ring = 1.0. grid (43, 128)
// ---------------------------------------------------------------------------
__global__ __launch_bounds__(256) void pA_k(const float* __restrict__ x) {
    const int v = blockIdx.x * 256 + threadIdx.x;
    if (v >= MAP_ / 4) return;
    const int m   = blockIdx.y;               // b*C + c
    const int p4  = v * 4;
    const int ph  = p4 / WP_;                 // WP_ % 4 == 0 -> same row
    const int pw0 = p4 - ph * WP_;
    const int ih  = ph - PAD_;

    const float* xm = x + (size_t)m * HW_;
    ushort4 r;
#pragma unroll
    for (int k = 0; k < 4; k++) {
        const int iw = pw0 + k - PAD_;
        float val = 1.0f;                     // zero-pad: exp2(s*0) = 1
        if (ih >= 0 && ih < H_ && iw >= 0 && iw < W_)
            val = exp2f(SCALE_IN * xm[ih * W_ + iw]);
        (&r.x)[k] = f2bf(val);
    }
    *(ushort4*)&g_P[(size_t)m * MAP_ + p4] = r;
}

// ---------------------------------------------------------------------------
// fused morphology: P tile -> Q (=1/dilate-sum) in LDS -> E, one 32x32 tile
// per block. grid (36 tiles, 32 c, 16 z=br*4+b), 256 threads.
// ---------------------------------------------------------------------------
template<int D>
__device__ __forceinline__ void morph_tile(int br, int b, int c, int tile,
                                           float* __restrict__ sP,
                                           float* __restrict__ sQ,
                                           float& out_s1, float& out_s2) {
    constexpr int PE = 32 + 4 * D;     // staged P extent
    constexpr int QE = 32 + 2 * D;     // computed Q extent
    const int th = tile / 6, tw = tile - th * 6;
    const int h0 = th * 32, w0 = tw * 32;
    const int tid = threadIdx.x;

    // block-uniform weights
    float cd[9], ce[9];
    const int cb = (br * C_ + c) * 9;
#pragma unroll
    for (int k = 0; k < 9; k++) {
        cd[k] = g_cw[cb + k];
        ce[k] = g_cw[1152 + cb + k];
    }

    // phase 1: stage P region (bf16 global -> f32 LDS)
    const unsigned short* Pg = g_P + (size_t)(b * C_ + c) * MAP_;
    for (int idx = tid; idx < PE * PE; idx += 256) {
        const int i = idx / PE, j = idx - i * PE;
        sP[idx] = bf2f(Pg[(h0 - 2 * D + i + PAD_) * WP_ + (w0 - 2 * D + j + PAD_)]);
    }
    __syncthreads();

    // phase 2: Q = 1 / sum(cd * P_taps); out-of-image cells := 1 (zero-pad)
    for (int idx = tid; idx < QE * QE; idx += 256) {
        const int qi = idx / QE, qj = idx - qi * QE;
        float s = 0.f;
#pragma unroll
        for (int i = 0; i < 3; i++)
#pragma unroll
            for (int j = 0; j < 3; j++)
                s = fmaf(cd[i * 3 + j], sP[(qi + i * D) * PE + qj + j * D], s);
        float q = __builtin_amdgcn_rcpf(s);
        const int hq = h0 - D + qi, wq = w0 - D + qj;
        if (hq < 0 || hq >= H_ || wq < 0 || wq >= W_) q = 1.0f;
        sQ[idx] = q;
    }
    __syncthreads();

    // phase 3: E = -(ln2/beta) * log2( sum(ce * Q_taps) ), 4 pixels/thread
    const int oi = tid >> 3;
    const int oj = (tid & 7) * 4;
    float vals[4];
#pragma unroll
    for (int u = 0; u < 4; u++) {
        float t = 0.f;
#pragma unroll
        for (int i = 0; i < 3; i++)
#pragma unroll
            for (int j = 0; j < 3; j++)
                t = fmaf(ce[i * 3 + j], sQ[(oi + i * D) * QE + oj + u + j * D], t);
        vals[u] = -SCALE_OUT * log2f(t);
    }
    ushort4 r;
    r.x = f2bf(vals[0]); r.y = f2bf(vals[1]);
    r.z = f2bf(vals[2]); r.w = f2bf(vals[3]);
    *(ushort4*)&g_E[(((size_t)br * B_ + b) * C_ + c) * HW_ + (h0 + oi) * W_ + w0 + oj] = r;

    out_s1 = vals[0] + vals[1] + vals[2] + vals[3];
    out_s2 = vals[0] * vals[0] + vals[1] * vals[1] + vals[2] * vals[2] + vals[3] * vals[3];
}

__global__ __launch_bounds__(256) void morph_k(void) {
    __shared__ float sP[48 * 48];
    __shared__ float sQ[40 * 40];
    const int z    = blockIdx.z;
    const int br   = z >> 2;
    const int b    = z & 3;
    const int c    = blockIdx.y;
    const int tile = blockIdx.x;

    float s1, s2;
    switch (br) {
        case 0: morph_tile<1>(br, b, c, tile, sP, sQ, s1, s2); break;
        case 1: morph_tile<2>(br, b, c, tile, sP, sQ, s1, s2); break;
        case 2: morph_tile<3>(br, b, c, tile, sP, sQ, s1, s2); break;
        default: morph_tile<4>(br, b, c, tile, sP, sQ, s1, s2); break;
    }

    // BN1 block partials (no atomics)
#pragma unroll
    for (int off = 32; off >= 1; off >>= 1) {
        s1 += __shfl_down(s1, off, 64);
        s2 += __shfl_down(s2, off, 64);
    }
    __shared__ float l1[4], l2[4];
    const int lane = threadIdx.x & 63;
    const int wv   = threadIdx.x >> 6;
    if (lane == 0) { l1[wv] = s1; l2[wv] = s2; }
    __syncthreads();
    if (threadIdx.x == 0) {
        const int slot = (br * C_ + c) * 144 + b * 36 + tile;
        g_p1[slot]       = l1[0] + l1[1] + l1[2] + l1[3];
        g_p1[NP1 + slot] = l2[0] + l2[1] + l2[2] + l2[3];
    }
}

// ---------------------------------------------------------------------------
// finalize BN1: reduce 144 partials per channel. grid = 128
// ---------------------------------------------------------------------------
__global__ __launch_bounds__(256) void fin1_k(const float* __restrict__ gs,
                                              const float* __restrict__ bs) {
    const int chan = blockIdx.x;
    const int base = chan * 144;
    float s1 = 0.0f, s2 = 0.0f;
    if (threadIdx.x < 144) {
        s1 = g_p1[base + threadIdx.x];
        s2 = g_p1[NP1 + base + threadIdx.x];
    }
#pragma unroll
    for (int off = 32; off >= 1; off >>= 1) {
        s1 += __shfl_down(s1, off, 64);
        s2 += __shfl_down(s2, off, 64);
    }
    __shared__ float l1[4], l2[4];
    const int lane = threadIdx.x & 63;
    const int wv   = threadIdx.x >> 6;
    if (lane == 0) { l1[wv] = s1; l2[wv] = s2; }
    __syncthreads();
    if (threadIdx.x == 0) {
        const float S1 = l1[0] + l1[1] + l1[2] + l1[3];
        const float S2 = l2[0] + l2[1] + l2[2] + l2[3];
        const float N  = (float)(B_ * HW_);
        const float mu = S1 / N;
        const float va = fmaxf(S2 / N - mu * mu, 0.0f);
        const float sc = gs[chan] * rsqrtf(va + EPS_);
        g_stats[chan]       = sc;
        g_stats[128 + chan] = bs[chan] - mu * sc;
    }
}

// ---------------------------------------------------------------------------
// fused BN1+ReLU + 1x1 conv + BN2 partials. grid (144, 4 og, 4 b).
// Weights/scales wave-uniform (scalar loads); E bf16 bits, shift-converted.
// ---------------------------------------------------------------------------
__global__ __launch_bounds__(256) void conv_k(void) {
    const int og = blockIdx.y;
    const int b  = blockIdx.z;
    const int p  = blockIdx.x * 256 + threadIdx.x;

    float acc[8];
#pragma unroll
    for (int k = 0; k < 8; k++) acc[k] = 0.0f;

#pragma unroll 4
    for (int ci = 0; ci < 128; ci++) {
        const int br = ci >> 5;
        const int c  = ci & 31;
        const unsigned short eu = g_E[(((size_t)br * B_ + b) * C_ + c) * HW_ + p];
        float v = bf2f(eu);
        v = fmaxf(fmaf(v, g_stats[ci], g_stats[128 + ci]), 0.0f);
        const float* wr = &g_Wt[ci * 32 + og * 8];
#pragma unroll
        for (int k = 0; k < 8; k++) acc[k] = fmaf(v, wr[k], acc[k]);
    }

    float* Yp = g_Y + ((size_t)b * C_ + og * 8) * HW_ + p;
#pragma unroll
    for (int k = 0; k < 8; k++) Yp[(size_t)k * HW_] = acc[k];

    __shared__ float l1[8][4], l2[8][4];
    const int lane = threadIdx.x & 63;
    const int wv   = threadIdx.x >> 6;
#pragma unroll
    for (int k = 0; k < 8; k++) {
        float s1 = acc[k];
        float s2 = acc[k] * acc[k];
#pragma unroll
        for (int off = 32; off >= 1; off >>= 1) {
            s1 += __shfl_down(s1, off, 64);
            s2 += __shfl_down(s2, off, 64);
        }
        if (lane == 0) { l1[k][wv] = s1; l2[k][wv] = s2; }
    }
    __syncthreads();
    if (threadIdx.x < 8) {
        const int k = threadIdx.x;
        const int chan = og * 8 + k;
        const int slot = chan * (B_ * 144) + b * 144 + blockIdx.x;
        g_p2[slot]       = l1[k][0] + l1[k][1] + l1[k][2] + l1[k][3];
        g_p2[NP2 + slot] = l2[k][0] + l2[k][1] + l2[k][2] + l2[k][3];
    }
}

// ---------------------------------------------------------------------------
// finalize BN2: reduce 576 partials per channel. grid = 32
// ---------------------------------------------------------------------------
__global__ __launch_bounds__(256) void fin2_k(const float* __restrict__ g,
                                              const float* __restrict__ bb) {
    const int chan = blockIdx.x;
    const int base = chan * (B_ * 144);
    float s1 = 0.0f, s2 = 0.0f;
    for (int i = threadIdx.x; i < B_ * 144; i += 256) {
        s1 += g_p2[base + i];
        s2 += g_p2[NP2 + base + i];
    }
#pragma unroll
    for (int off = 32; off >= 1; off >>= 1) {
        s1 += __shfl_down(s1, off, 64);
        s2 += __shfl_down(s2, off, 64);
    }
    __shared__ float l1[4], l2[4];
    const int lane = threadIdx.x & 63;
    const int wv   = threadIdx.x >> 6;
    if (lane == 0) { l1[wv] = s1; l2[wv] = s2; }
    __syncthreads();
    if (threadIdx.x == 0) {
        const float S1 = l1[0] + l1[1] + l1[2] + l1[3];
        const float S2 = l2[0] + l2[1] + l2[2] + l2[3];
        const float N  = (float)(B_ * HW_);
        const float mu = S1 / N;
        const float va = fmaxf(S2 / N - mu * mu, 0.0f);
        const float sc = g[chan] * rsqrtf(va + EPS_);
        g_stats[256 + chan] = sc;
        g_stats[288 + chan] = bb[chan] - mu * sc;
    }
}

// ---------------------------------------------------------------------------
// final: BN2 + ReLU -> f32 (float4). grid (36, 32, 4)
// ---------------------------------------------------------------------------
__global__ __launch_bounds__(256) void final_k(float* __restrict__ out) {
    const int c = blockIdx.y;
    const int b = blockIdx.z;
    const size_t base = (size_t)(b * C_ + c) * HW_ + (blockIdx.x * 256 + threadIdx.x) * 4;
    const float sc = g_stats[256 + c];
    const float sh = g_stats[288 + c];
    const float4 v = *(const float4*)&g_Y[base];
    float4 r;
    r.x = fmaxf(v.x * sc + sh, 0.0f);
    r.y = fmaxf(v.y * sc + sh, 0.0f);
    r.z = fmaxf(v.z * sc + sh, 0.0f);
    r.w = fmaxf(v.w * sc + sh, 0.0f);
    *(float4*)&out[base] = r;
}

// ---------------------------------------------------------------------------
extern "C" void kernel_launch(void* const* d_in, const int* in_sizes, int n_in,
                              void* d_out, int out_size, void* d_ws, size_t ws_size,
                              hipStream_t stream) {
    const float* x  = (const float*)d_in[0];
    const float* wd = (const float*)d_in[1];
    const float* we = (const float*)d_in[2];
    const float* gs = (const float*)d_in[3];
    const float* bs = (const float*)d_in[4];
    const float* Wc = (const float*)d_in[5];
    const float* g  = (const float*)d_in[6];
    const float* bb = (const float*)d_in[7];

    prep_k<<<1, 256, 0, stream>>>(wd, we, Wc);
    pA_k<<<dim3((MAP_ / 4 + 255) / 256, B_ * C_), 256, 0, stream>>>(x);
    morph_k<<<dim3(36, C_, 16), 256, 0, stream>>>();
    fin1_k<<<128, 256, 0, stream>>>(gs, bs);
    conv_k<<<dim3(HW_ / 256, 4, B_), 256, 0, stream>>>();
    fin2_k<<<32, 256, 0, stream>>>(g, bb);
    final_k<<<dim3(HW_ / 1024, C_, B_), 256, 0, stream>>>((float*)d_out);
}

// Round 10
// 115.419 us; speedup vs baseline: 2.3360x; 1.1579x over previous
//
#include <hip/hip_runtime.h>
#include <hip/hip_bf16.h>

// Problem constants
#define B_   4
#define C_   32
#define H_   192
#define W_   192
#define HW_  (H_ * W_)          // 36864
#define EPS_ 1e-5f

#define SCALE_IN  21.640425613334453f   // beta/ln2
#define SCALE_OUT 0.046209812037329687f // ln2/beta

#define NP1 (128 * 576)         // chan * (4 b * 36 tiles * 4 waves)
#define NP2 (32 * 4 * 144)

// bf16 <-> f32 helpers (bit-exact shift load, RNE store)
__device__ __forceinline__ float bf2f(unsigned short u) {
    return __uint_as_float((unsigned int)u << 16);
}
__device__ __forceinline__ unsigned short f2bf(float f) {
    const unsigned int u = __float_as_uint(f);
    return (unsigned short)((u + 0x7fffu + ((u >> 16) & 1u)) >> 16);
}

// ---------------------------------------------------------------------------
// Scratch (module globals; no atomics anywhere).
//  g_cw[0..1151] = 2^(s*wd), [1152..2303] = 2^(s*we)   ((br*C+c)*9+tap)
//  g_Wt[ci*32+k] = Wc[k*128+ci]
//  g_stats[0..127] sc1 [128..255] sh1 [256..287] sc2 [288..319] sh2
//  g_E : erode out, bf16 bits, [(br*B+b)*C+c][p]
//  g_Y : conv out,  f32,  [(b*C+o)][p]
// ---------------------------------------------------------------------------
__device__ float          g_cw[2304];
__device__ float          g_Wt[4096];
__device__ float          g_stats[320];
__device__ float          g_p1[2 * NP1];
__device__ float          g_p2[2 * NP2];
__device__ __attribute__((aligned(16))) unsigned short g_E[(size_t)4 * B_ * C_ * HW_]; // 37.75 MB
__device__ __attribute__((aligned(16))) float          g_Y[(size_t)B_ * C_ * HW_];     // 18.87 MB

// ---------------------------------------------------------------------------
// prep: exponentiate morphology weights + transpose conv weights
// ---------------------------------------------------------------------------
__global__ void prep_k(const float* __restrict__ wd, const float* __restrict__ we,
                       const float* __restrict__ Wc) {
    for (int i = threadIdx.x; i < 2304; i += 256) {
        const float v = (i < 1152) ? wd[i] : we[i - 1152];
        g_cw[i] = exp2f(SCALE_IN * v);
    }
    for (int i = threadIdx.x; i < 4096; i += 256) {
        const int ci = i >> 5;
        const int k  = i & 31;
        g_Wt[i] = Wc[(size_t)k * 128 + ci];
    }
}

// ---------------------------------------------------------------------------
// One morphology branch (dilate-recip + erode) on a staged 48x48 P tile.
// sP[48*48]: P = 2^(s*x), halo +-8, out-of-image = 1.0 (zero-pad).
// sQ[40*40]: Q = 1/dilate-sum (row stride fixed 40).
// All tap/window indices compile-time via D. 4 cells per thread, f4 LDS ops.
// ---------------------------------------------------------------------------
template<int D>
__device__ __forceinline__ void morph_branch(int b, int c, int h0, int w0,
                                             int slotbase,
                                             const float* __restrict__ sP,
                                             float* __restrict__ sQ) {
    constexpr int QE   = 32 + 2 * D;          // Q extent needed by this branch
    constexpr int QEG  = (QE + 3) / 4;        // float4 groups per Q row
    constexpr int UNITS = QE * QEG;           // <= 400
    constexpr int POFF = 8 - 2 * D;           // window start col offset in sP
    constexpr int AB   = POFF & ~3;           // aligned base
    constexpr int OFF  = POFF & 3;            // start within reg buffer
    constexpr int NR   = (OFF + 2 * D + 4 + 3) / 4;  // f4 reads/row (phase 2)
    constexpr int NR3  = (2 * D + 4 + 3) / 4;        // f4 reads/row (phase 3)
    constexpr int br   = D - 1;

    const int tid = threadIdx.x;
    const int cb  = (br * C_ + c) * 9;

    // ---- phase 2: Q = rcp( sum cd * P_taps ); out-of-image cells := 1 ----
    {
        float cd[9];
#pragma unroll
        for (int k = 0; k < 9; k++) cd[k] = g_cw[cb + k];

#pragma unroll
        for (int it = 0; it < 2; ++it) {
            const int unit = tid + it * 256;
            if (unit < UNITS) {
                const int qi = unit / QEG;                 // compile-time magic div
                const int qj = (unit - qi * QEG) * 4;
                float a0 = 0.f, a1 = 0.f, a2 = 0.f, a3 = 0.f;
#pragma unroll
                for (int i = 0; i < 3; i++) {
                    const float* rp = &sP[(qi + 8 + (i - 2) * D) * 48 + qj + AB];
                    float buf[NR * 4];
#pragma unroll
                    for (int r = 0; r < NR; r++)
                        *(float4*)&buf[r * 4] = *(const float4*)&rp[r * 4];
#pragma unroll
                    for (int j = 0; j < 3; j++) {
                        const float wgt = cd[i * 3 + j];
                        a0 = fmaf(wgt, buf[OFF + j * D + 0], a0);
                        a1 = fmaf(wgt, buf[OFF + j * D + 1], a1);
                        a2 = fmaf(wgt, buf[OFF + j * D + 2], a2);
                        a3 = fmaf(wgt, buf[OFF + j * D + 3], a3);
                    }
                }
                float q0 = __builtin_amdgcn_rcpf(a0);
                float q1 = __builtin_amdgcn_rcpf(a1);
                float q2 = __builtin_amdgcn_rcpf(a2);
                float q3 = __builtin_amdgcn_rcpf(a3);
                const int hq = h0 - D + qi;
                const int wq = w0 - D + qj;
                const bool rowo = (hq < 0) || (hq >= H_);
                q0 = (rowo || (wq + 0 < 0) || (wq + 0 >= W_)) ? 1.0f : q0;
                q1 = (rowo || (wq + 1 < 0) || (wq + 1 >= W_)) ? 1.0f : q1;
                q2 = (rowo || (wq + 2 < 0) || (wq + 2 >= W_)) ? 1.0f : q2;
                q3 = (rowo || (wq + 3 < 0) || (wq + 3 >= W_)) ? 1.0f : q3;
                *(float4*)&sQ[qi * 40 + qj] = make_float4(q0, q1, q2, q3);
            }
        }
    }
    __syncthreads();

    // ---- phase 3: E = -(ln2/beta)*log2( sum ce * Q_taps ), 4 px/thread ----
    {
        float ce[9];
#pragma unroll
        for (int k = 0; k < 9; k++) ce[k] = g_cw[1152 + cb + k];

        const int oi = tid >> 3;
        const int oj = (tid & 7) * 4;
        float t0 = 0.f, t1 = 0.f, t2 = 0.f, t3 = 0.f;
#pragma unroll
        for (int i = 0; i < 3; i++) {
            const float* rq = &sQ[(oi + i * D) * 40 + oj];
            float buf[NR3 * 4];
#pragma unroll
            for (int r = 0; r < NR3; r++)
                *(float4*)&buf[r * 4] = *(const float4*)&rq[r * 4];
#pragma unroll
            for (int j = 0; j < 3; j++) {
                const float wgt = ce[i * 3 + j];
                t0 = fmaf(wgt, buf[j * D + 0], t0);
                t1 = fmaf(wgt, buf[j * D + 1], t1);
                t2 = fmaf(wgt, buf[j * D + 2], t2);
                t3 = fmaf(wgt, buf[j * D + 3], t3);
            }
        }
        const float e0 = -SCALE_OUT * log2f(t0);
        const float e1 = -SCALE_OUT * log2f(t1);
        const float e2 = -SCALE_OUT * log2f(t2);
        const float e3 = -SCALE_OUT * log2f(t3);

        ushort4 r4;
        r4.x = f2bf(e0); r4.y = f2bf(e1); r4.z = f2bf(e2); r4.w = f2bf(e3);
        *(ushort4*)&g_E[(((size_t)br * B_ + b) * C_ + c) * HW_
                        + (size_t)(h0 + oi) * W_ + w0 + oj] = r4;

        // per-wave BN1 partials straight to private global slots
        float s1 = e0 + e1 + e2 + e3;
        float s2 = e0 * e0 + e1 * e1 + e2 * e2 + e3 * e3;
#pragma unroll
        for (int off = 32; off >= 1; off >>= 1) {
            s1 += __shfl_down(s1, off, 64);
            s2 += __shfl_down(s2, off, 64);
        }
        if ((tid & 63) == 0) {
            const int slot = (br * C_ + c) * 576 + slotbase + (tid >> 6);
            g_p1[slot]       = s1;
            g_p1[NP1 + slot] = s2;
        }
    }
    __syncthreads();   // protect sQ before next branch's phase 2
}

// ---------------------------------------------------------------------------
// fused all-branch morphology. grid (36 tiles, 32 c, 4 b), 256 threads.
// Stages P once (from x, halo 8, pad 1.0), runs branches D=1..4.
// ---------------------------------------------------------------------------
__global__ __launch_bounds__(256) void morph_k(const float* __restrict__ x) {
    __shared__ float sP[48 * 48];
    __shared__ float sQ[40 * 40];
    const int tile = blockIdx.x;
    const int c    = blockIdx.y;
    const int b    = blockIdx.z;
    const int th   = tile / 6;
    const int tw   = tile - th * 6;
    const int h0   = th * 32, w0 = tw * 32;

    // stage: sP = 2^(s*x) with clamped loads + pad-select (no divergence)
    const float* xm = x + (size_t)(b * C_ + c) * HW_;
    for (int idx = threadIdx.x; idx < 48 * 48; idx += 256) {
        const int r  = idx / 48, q = idx - r * 48;
        const int ih = h0 - 8 + r, iw = w0 - 8 + q;
        const int ihc = min(max(ih, 0), H_ - 1);
        const int iwc = min(max(iw, 0), W_ - 1);
        const float xv = xm[ihc * W_ + iwc];
        const bool inb = (ih == ihc) && (iw == iwc);
        sP[idx] = inb ? exp2f(SCALE_IN * xv) : 1.0f;
    }
    __syncthreads();

    const int slotbase = (b * 36 + tile) * 4;
    morph_branch<1>(b, c, h0, w0, slotbase, sP, sQ);
    morph_branch<2>(b, c, h0, w0, slotbase, sP, sQ);
    morph_branch<3>(b, c, h0, w0, slotbase, sP, sQ);
    morph_branch<4>(b, c, h0, w0, slotbase, sP, sQ);
}

// ---------------------------------------------------------------------------
// finalize BN1: reduce 576 partials per channel. grid = 128
// ---------------------------------------------------------------------------
__global__ __launch_bounds__(256) void fin1_k(const float* __restrict__ gs,
                                              const float* __restrict__ bs) {
    const int chan = blockIdx.x;
    const int base = chan * 576;
    float s1 = 0.0f, s2 = 0.0f;
    for (int i = threadIdx.x; i < 576; i += 256) {
        s1 += g_p1[base + i];
        s2 += g_p1[NP1 + base + i];
    }
#pragma unroll
    for (int off = 32; off >= 1; off >>= 1) {
        s1 += __shfl_down(s1, off, 64);
        s2 += __shfl_down(s2, off, 64);
    }
    __shared__ float l1[4], l2[4];
    const int lane = threadIdx.x & 63;
    const int wv   = threadIdx.x >> 6;
    if (lane == 0) { l1[wv] = s1; l2[wv] = s2; }
    __syncthreads();
    if (threadIdx.x == 0) {
        const float S1 = l1[0] + l1[1] + l1[2] + l1[3];
        const float S2 = l2[0] + l2[1] + l2[2] + l2[3];
        const float N  = (float)(B_ * HW_);
        const float mu = S1 / N;
        const float va = fmaxf(S2 / N - mu * mu, 0.0f);
        const float sc = gs[chan] * rsqrtf(va + EPS_);
        g_stats[chan]       = sc;
        g_stats[128 + chan] = bs[chan] - mu * sc;
    }
}

// ---------------------------------------------------------------------------
// fused BN1+ReLU + 1x1 conv + BN2 partials. grid (144, 4 og, 4 b).
// Weights/scales wave-uniform (scalar loads); E bf16 bits, shift-converted.
// ---------------------------------------------------------------------------
__global__ __launch_bounds__(256) void conv_k(void) {
    const int og = blockIdx.y;
    const int b  = blockIdx.z;
    const int p  = blockIdx.x * 256 + threadIdx.x;

    float acc[8];
#pragma unroll
    for (int k = 0; k < 8; k++) acc[k] = 0.0f;

#pragma unroll 4
    for (int ci = 0; ci < 128; ci++) {
        const int br = ci >> 5;
        const int c  = ci & 31;
        const unsigned short eu = g_E[(((size_t)br * B_ + b) * C_ + c) * HW_ + p];
        float v = bf2f(eu);
        v = fmaxf(fmaf(v, g_stats[ci], g_stats[128 + ci]), 0.0f);
        const float* wr = &g_Wt[ci * 32 + og * 8];
#pragma unroll
        for (int k = 0; k < 8; k++) acc[k] = fmaf(v, wr[k], acc[k]);
    }

    float* Yp = g_Y + ((size_t)b * C_ + og * 8) * HW_ + p;
#pragma unroll
    for (int k = 0; k < 8; k++) Yp[(size_t)k * HW_] = acc[k];

    __shared__ float l1[8][4], l2[8][4];
    const int lane = threadIdx.x & 63;
    const int wv   = threadIdx.x >> 6;
#pragma unroll
    for (int k = 0; k < 8; k++) {
        float s1 = acc[k];
        float s2 = acc[k] * acc[k];
#pragma unroll
        for (int off = 32; off >= 1; off >>= 1) {
            s1 += __shfl_down(s1, off, 64);
            s2 += __shfl_down(s2, off, 64);
        }
        if (lane == 0) { l1[k][wv] = s1; l2[k][wv] = s2; }
    }
    __syncthreads();
    if (threadIdx.x < 8) {
        const int k = threadIdx.x;
        const int chan = og * 8 + k;
        const int slot = chan * (B_ * 144) + b * 144 + blockIdx.x;
        g_p2[slot]       = l1[k][0] + l1[k][1] + l1[k][2] + l1[k][3];
        g_p2[NP2 + slot] = l2[k][0] + l2[k][1] + l2[k][2] + l2[k][3];
    }
}

// ---------------------------------------------------------------------------
// finalize BN2: reduce 576 partials per channel. grid = 32
// ---------------------------------------------------------------------------
__global__ __launch_bounds__(256) void fin2_k(const float* __restrict__ g,
                                              const float* __restrict__ bb) {
    const int chan = blockIdx.x;
    const int base = chan * (B_ * 144);
    float s1 = 0.0f, s2 = 0.0f;
    for (int i = threadIdx.x; i < B_ * 144; i += 256) {
        s1 += g_p2[base + i];
        s2 += g_p2[NP2 + base + i];
    }
#pragma unroll
    for (int off = 32; off >= 1; off >>= 1) {
        s1 += __shfl_down(s1, off, 64);
        s2 += __shfl_down(s2, off, 64);
    }
    __shared__ float l1[4], l2[4];
    const int lane = threadIdx.x & 63;
    const int wv   = threadIdx.x >> 6;
    if (lane == 0) { l1[wv] = s1; l2[wv] = s2; }
    __syncthreads();
    if (threadIdx.x == 0) {
        const float S1 = l1[0] + l1[1] + l1[2] + l1[3];
        const float S2 = l2[0] + l2[1] + l2[2] + l2[3];
        const float N  = (float)(B_ * HW_);
        const float mu = S1 / N;
        const float va = fmaxf(S2 / N - mu * mu, 0.0f);
        const float sc = g[chan] * rsqrtf(va + EPS_);
        g_stats[256 + chan] = sc;
        g_stats[288 + chan] = bb[chan] - mu * sc;
    }
}

// ---------------------------------------------------------------------------
// final: BN2 + ReLU -> f32 (float4). grid (36, 32, 4)
// ---------------------------------------------------------------------------
__global__ __launch_bounds__(256) void final_k(float* __restrict__ out) {
    const int c = blockIdx.y;
    const int b = blockIdx.z;
    const size_t base = (size_t)(b * C_ + c) * HW_ + (blockIdx.x * 256 + threadIdx.x) * 4;
    const float sc = g_stats[256 + c];
    const float sh = g_stats[288 + c];
    const float4 v = *(const float4*)&g_Y[base];
    float4 r;
    r.x = fmaxf(v.x * sc + sh, 0.0f);
    r.y = fmaxf(v.y * sc + sh, 0.0f);
    r.z = fmaxf(v.z * sc + sh, 0.0f);
    r.w = fmaxf(v.w * sc + sh, 0.0f);
    *(float4*)&out[base] = r;
}

// ---------------------------------------------------------------------------
extern "C" void kernel_launch(void* const* d_in, const int* in_sizes, int n_in,
                              void* d_out, int out_size, void* d_ws, size_t ws_size,
                              hipStream_t stream) {
    const float* x  = (const float*)d_in[0];
    const float* wd = (const float*)d_in[1];
    const float* we = (const float*)d_in[2];
    const float* gs = (const float*)d_in[3];
    const float* bs = (const float*)d_in[4];
    const float* Wc = (const float*)d_in[5];
    const float* g  = (const float*)d_in[6];
    const float* bb = (const float*)d_in[7];

    prep_k<<<1, 256, 0, stream>>>(wd, we, Wc);
    morph_k<<<dim3(36, C_, B_), 256, 0, stream>>>(x);
    fin1_k<<<128, 256, 0, stream>>>(gs, bs);
    conv_k<<<dim3(HW_ / 256, 4, B_), 256, 0, stream>>>();
    fin2_k<<<32, 256, 0, stream>>>(g, bb);
    final_k<<<dim3(HW_ / 1024, C_, B_), 256, 0, stream>>>((float*)d_out);
}